// Round 8
// baseline (758.279 us; speedup 1.0000x reference)
//
#include <hip/hip_runtime.h>
#include <hip/hip_fp16.h>
#include <math.h>

// ---------------------------------------------------------------------------
// DeepECCNet: 3-layer gated graph conv + t-gate + MLP head.
// v8: (a) CSR fill writes ONE 8B {src,ea} record per edge (v7: two 4B
//     scatters to two arrays -> 154 MB WRITE_SIZE, 128 us); gates computed
//     inline in agg (gbuf/gates_kernel removed). (b) h stored fp16
//     everywhere (consumers already rounded to fp16 -> numerically free,
//     halves h traffic). (c) agg edge-loop unroll 4->8 (VGPR was 12).
//     (d) count folded into cvt.
// ---------------------------------------------------------------------------

typedef _Float16 f16x8 __attribute__((ext_vector_type(8)));
typedef float f32x4 __attribute__((ext_vector_type(4)));

__device__ __forceinline__ float sigmoidf_(float v) { return 1.f / (1.f + expf(-v)); }

__global__ void sentinel_kernel(float* __restrict__ out, int n, float val) {
  int i = blockIdx.x * 256 + threadIdx.x;
  if (i < n) out[i] = val;
}

__global__ void zero_kernel(int* __restrict__ p, int n) {
  int i = blockIdx.x * 256 + threadIdx.x;
  if (i < n) p[i] = 0;
}

// ---- edge-index dtype hedge: int64 has all-zero hi (odd) words -------------
__global__ void detect_kernel(const int* __restrict__ ei, int* __restrict__ flag) {
  if (threadIdx.x == 0 && blockIdx.x == 0) {
    int all0 = 1;
    for (int i = 1; i < 512; i += 2) {
      if (ei[i] != 0) { all0 = 0; break; }
    }
    *flag = all0;
  }
}

// ---- cvt + degree count in one pass ----------------------------------------
__global__ void cvt_kernel(const int* __restrict__ ei, int E, int n,
                           const int* __restrict__ flag,
                           int* __restrict__ src32, int* __restrict__ tgt32,
                           int* __restrict__ counts) {
  int e = blockIdx.x * blockDim.x + threadIdx.x;
  if (e >= E) return;
  int s, t;
  if (*flag) {
    const long long* e64 = (const long long*)ei;
    s = (int)e64[e];
    t = (int)e64[(size_t)E + e];
  } else {
    s = ei[e];
    t = ei[(size_t)E + e];
  }
  src32[e] = s;
  tgt32[e] = t;
  if ((unsigned)t < (unsigned)n) atomicAdd(&counts[t], 1);
}

__global__ void scan1_kernel(const int* __restrict__ counts, int n,
                             int* __restrict__ starts, int* __restrict__ bsums) {
  __shared__ int tmp[256];
  int i = blockIdx.x * 256 + threadIdx.x;
  int v = (i < n) ? counts[i] : 0;
  tmp[threadIdx.x] = v;
  __syncthreads();
  for (int off = 1; off < 256; off <<= 1) {
    int t = (threadIdx.x >= (unsigned)off) ? tmp[threadIdx.x - off] : 0;
    __syncthreads();
    tmp[threadIdx.x] += t;
    __syncthreads();
  }
  if (i < n) starts[i] = tmp[threadIdx.x] - v;  // exclusive
  if (threadIdx.x == 255) bsums[blockIdx.x] = tmp[255];
}

__global__ void scan2_kernel(int* __restrict__ bsums, int nb) {
  __shared__ int tmp[512];
  int v = (threadIdx.x < (unsigned)nb) ? bsums[threadIdx.x] : 0;
  tmp[threadIdx.x] = v;
  __syncthreads();
  for (int off = 1; off < 512; off <<= 1) {
    int t = (threadIdx.x >= (unsigned)off) ? tmp[threadIdx.x - off] : 0;
    __syncthreads();
    tmp[threadIdx.x] += t;
    __syncthreads();
  }
  if (threadIdx.x < (unsigned)nb) bsums[threadIdx.x] = tmp[threadIdx.x] - v;  // exclusive
}

__global__ void scan3_kernel(int* __restrict__ starts, const int* __restrict__ bsums,
                             int n, int* __restrict__ cursor) {
  int i = blockIdx.x * 256 + threadIdx.x;
  if (i < n) {
    int s = starts[i] + bsums[blockIdx.x];
    starts[i] = s;
    cursor[i] = s;
  }
}

// ---- fill: one 8B {src_as_float, ea} record per edge -----------------------
__global__ void fill_kernel(const int* __restrict__ src, const int* __restrict__ tgt,
                            const float* __restrict__ ea, int E, int n,
                            int* __restrict__ cursor, float2* __restrict__ csr) {
  int e = blockIdx.x * blockDim.x + threadIdx.x;
  if (e < E) {
    unsigned t = (unsigned)tgt[e];
    if (t >= (unsigned)n) return;
    int slot = atomicAdd(&cursor[t], 1);
    if ((unsigned)slot < (unsigned)E)
      csr[slot] = make_float2(__int_as_float(src[e]), ea[e]);
  }
}

// ---- h0 = fp16(x[:, 1:]); x0 = x[:, 0] -------------------------------------
__global__ void slice_kernel(const float* __restrict__ x, _Float16* __restrict__ h,
                             float* __restrict__ x0, int n) {
  int idx = blockIdx.x * blockDim.x + threadIdx.x;
  if (idx < n * 128) {
    int node = idx >> 7;
    int k = idx & 127;
    h[idx] = (_Float16)x[(size_t)node * 129 + 1 + k];
  }
  if (idx < n) x0[idx] = x[(size_t)idx * 129];
}

// ---- unified MFMA head: out = sigmoid( relu(h@W1[hrow0:hrow0+128] +
//        extra*W1[xrow] + b1) @ w2 + b2 )  — tnet: hrow0=1,xrow=0,extra=x0;
//        mlp: hrow0=0,xrow=128,extra=t.
__global__ __launch_bounds__(256) void head_mfma_kernel(const _Float16* __restrict__ h,
    const float* __restrict__ extra, const float* __restrict__ W1,
    const float* __restrict__ b1, const float* __restrict__ w2,
    const float* __restrict__ b2, float* __restrict__ out, int n,
    int hrow0, int xrow) {
  __shared__ __align__(16) _Float16 sB[4 * 4 * 64 * 8];  // 16 KB, B-frag order
  __shared__ float sWx[64], sB1[64], sW2[64];
  for (int idx = threadIdx.x; idx < 8192; idx += 256) {
    int k = idx >> 6, col = idx & 63;
    float w = W1[(size_t)(hrow0 + k) * 64 + col];
    int ks = k >> 5, quad = (k >> 3) & 3, j = k & 7;
    int nt = col >> 4, cl = col & 15;
    sB[(((ks * 4 + nt) * 64) + quad * 16 + cl) * 8 + j] = (_Float16)w;
  }
  if (threadIdx.x < 64) {
    sWx[threadIdx.x] = W1[(size_t)xrow * 64 + threadIdx.x];
    sB1[threadIdx.x] = b1[threadIdx.x];
    sW2[threadIdx.x] = w2[threadIdx.x];
  }
  __syncthreads();
  int wv = threadIdx.x >> 6, lane = threadIdx.x & 63;
  int quad = lane >> 4, l15 = lane & 15;
  int n0 = (blockIdx.x * 4 + wv) * 16;
  if (n0 >= n) return;
  int node_a = min(n0 + l15, n - 1);
  const _Float16* hrow = h + (size_t)node_a * 128 + quad * 8;

  f32x4 acc[4];
#pragma unroll
  for (int t = 0; t < 4; t++) acc[t] = (f32x4){0.f, 0.f, 0.f, 0.f};
  for (int ks = 0; ks < 4; ks++) {
    f16x8 afrag = *(const f16x8*)(hrow + ks * 32);
    const f16x8* bp = (const f16x8*)sB;
#pragma unroll
    for (int t = 0; t < 4; t++) {
      f16x8 bfrag = bp[(ks * 4 + t) * 64 + lane];
      acc[t] = __builtin_amdgcn_mfma_f32_16x16x32_f16(afrag, bfrag, acc[t], 0, 0, 0);
    }
  }
  float b2v = b2[0];
  float xv[4], part[4] = {0.f, 0.f, 0.f, 0.f};
#pragma unroll
  for (int r = 0; r < 4; r++) xv[r] = extra[min(n0 + quad * 4 + r, n - 1)];
#pragma unroll
  for (int t = 0; t < 4; t++) {
    int col = t * 16 + l15;
    float wx = sWx[col], bb = sB1[col], w2v = sW2[col];
#pragma unroll
    for (int r = 0; r < 4; r++) {
      float u = fmaxf(acc[t][r] + xv[r] * wx + bb, 0.f);
      part[r] += u * w2v;
    }
  }
#pragma unroll
  for (int r = 0; r < 4; r++) {
    float p = part[r];
    p += __shfl_xor(p, 1); p += __shfl_xor(p, 2);
    p += __shfl_xor(p, 4); p += __shfl_xor(p, 8);
    int node = n0 + quad * 4 + r;
    if (l15 == 0 && node < n) out[node] = sigmoidf_(p + b2v);
  }
}

// ---- MFMA GEMM: ht16 = f16(h16 @ W + b) ------------------------------------
__global__ __launch_bounds__(256) void gemm_mfma_kernel(const _Float16* __restrict__ h,
    const float* __restrict__ Wg, const float* __restrict__ b,
    _Float16* __restrict__ out16, int n) {
  __shared__ __align__(16) _Float16 sB[4 * 8 * 64 * 8];  // 32 KB
  for (int i = threadIdx.x; i < 4096; i += 256) {  // i = float4 index over W
    int k = i >> 5;
    int n4 = (i & 31) * 4;
    float4 w4 = ((const float4*)Wg)[i];
    int ks = k >> 5, quad = (k >> 3) & 3, j = k & 7;
#pragma unroll
    for (int c = 0; c < 4; c++) {
      int col = n4 + c;
      int nt = col >> 4, cl = col & 15;
      sB[(((ks * 8 + nt) * 64) + quad * 16 + cl) * 8 + j] =
          (_Float16)((const float*)&w4)[c];
    }
  }
  __syncthreads();
  int wv = threadIdx.x >> 6, lane = threadIdx.x & 63;
  int quad = lane >> 4, l15 = lane & 15;
  int n0 = (blockIdx.x * 4 + wv) * 16;
  if (n0 >= n) return;
  int node_a = min(n0 + l15, n - 1);
  const _Float16* hrow = h + (size_t)node_a * 128 + quad * 8;

  f32x4 acc[8];
#pragma unroll
  for (int t = 0; t < 8; t++) acc[t] = (f32x4){0.f, 0.f, 0.f, 0.f};

  for (int ks = 0; ks < 4; ks++) {
    f16x8 afrag = *(const f16x8*)(hrow + ks * 32);
    const f16x8* bp = (const f16x8*)(sB + ks * 8 * 64 * 8);
#pragma unroll
    for (int t = 0; t < 8; t++) {
      f16x8 bfrag = bp[t * 64 + lane];
      acc[t] = __builtin_amdgcn_mfma_f32_16x16x32_f16(afrag, bfrag, acc[t], 0, 0, 0);
    }
  }
#pragma unroll
  for (int t = 0; t < 8; t++) {
    float bias = b[t * 16 + l15];
#pragma unroll
    for (int r = 0; r < 4; r++) {
      int node = n0 + quad * 4 + r;
      if (node < n)
        out16[(size_t)node * 128 + t * 16 + l15] = (_Float16)(acc[t][r] + bias);
    }
  }
}

// ---- aggregation over fp16 rows; gates inline; unroll x8 -------------------
// h' = f16( relu( (sig(w)*ht[v] + sum_e sig(ea_e*w)*ht[src_e]) / (deg+1) ) )
__global__ __launch_bounds__(256) void agg_kernel(const __half2* __restrict__ ht,
    const float2* __restrict__ csr, const int* __restrict__ starts,
    const int* __restrict__ counts, const float* __restrict__ wp,
    __half2* __restrict__ hout, int n) {
  int wv = threadIdx.x >> 6, lane = threadIdx.x & 63;
  int node = blockIdx.x * 4 + wv;
  if (node >= n) return;
  int s = starts[node], c = counts[node];
  float w = wp[0];
  float gs = sigmoidf_(w);
  float2 v0 = __half22float2(ht[(size_t)node * 64 + lane]);
  float ax = gs * v0.x, ay = gs * v0.y;
  float bx = 0.f, by = 0.f;
  int j = 0;
  for (; j + 8 <= c; j += 8) {
    float2 pr[8];
#pragma unroll
    for (int u = 0; u < 8; u++) pr[u] = csr[s + j + u];
    int sn[8];
    float g[8];
#pragma unroll
    for (int u = 0; u < 8; u++) {
      sn[u] = min(max(__float_as_int(pr[u].x), 0), n - 1);
      g[u] = sigmoidf_(pr[u].y * w);
    }
    float2 f[8];
#pragma unroll
    for (int u = 0; u < 8; u++) f[u] = __half22float2(ht[(size_t)sn[u] * 64 + lane]);
#pragma unroll
    for (int u = 0; u < 8; u += 2) {
      ax += g[u] * f[u].x;         ay += g[u] * f[u].y;
      bx += g[u + 1] * f[u + 1].x; by += g[u + 1] * f[u + 1].y;
    }
  }
  for (; j < c; j++) {
    float2 pr = csr[s + j];
    int sn = min(max(__float_as_int(pr.x), 0), n - 1);
    float g = sigmoidf_(pr.y * w);
    float2 f = __half22float2(ht[(size_t)sn * 64 + lane]);
    ax += g * f.x; ay += g * f.y;
  }
  ax += bx; ay += by;
  float inv = 1.f / (float)(c + 1);
  ax = fmaxf(ax * inv, 0.f);
  ay = fmaxf(ay * inv, 0.f);
  hout[(size_t)node * 64 + lane] = __floats2half2_rn(ax, ay);
}

// ---------------------------------------------------------------------------
extern "C" void kernel_launch(void* const* d_in, const int* in_sizes, int n_in,
                              void* d_out, int out_size, void* d_ws, size_t ws_size,
                              hipStream_t stream) {
  int ob = (out_size + 255) / 256;

  const float *x, *ea, *l1W, *l1b, *l2W, *l2b, *t1W, *t1b, *t2W, *t2b;
  const float *convW[3], *convb[3], *edgew[3];
  const int* ei;

  if (n_in == 20) {          // tuples flattened to separate entries
    x = (const float*)d_in[0]; ei = (const int*)d_in[1]; ea = (const float*)d_in[2];
    for (int l = 0; l < 3; l++) {
      convW[l] = (const float*)d_in[3 + l];
      convb[l] = (const float*)d_in[6 + l];
      edgew[l] = (const float*)d_in[9 + l];
    }
    l1W = (const float*)d_in[12]; l1b = (const float*)d_in[13];
    l2W = (const float*)d_in[14]; l2b = (const float*)d_in[15];
    t1W = (const float*)d_in[16]; t1b = (const float*)d_in[17];
    t2W = (const float*)d_in[18]; t2b = (const float*)d_in[19];
  } else if (n_in == 14) {   // each tuple is ONE concatenated buffer
    x = (const float*)d_in[0]; ei = (const int*)d_in[1]; ea = (const float*)d_in[2];
    const float* cw = (const float*)d_in[3];
    const float* cb = (const float*)d_in[4];
    const float* ew = (const float*)d_in[5];
    for (int l = 0; l < 3; l++) {
      convW[l] = cw + (size_t)l * 128 * 128;
      convb[l] = cb + (size_t)l * 128;
      edgew[l] = ew + l;
    }
    l1W = (const float*)d_in[6];  l1b = (const float*)d_in[7];
    l2W = (const float*)d_in[8];  l2b = (const float*)d_in[9];
    t1W = (const float*)d_in[10]; t1b = (const float*)d_in[11];
    t2W = (const float*)d_in[12]; t2b = (const float*)d_in[13];
  } else {
    sentinel_kernel<<<ob, 256, 0, stream>>>((float*)d_out, out_size,
                                            900.0f + (float)n_in);
    return;
  }

  int n = in_sizes[0] / 129;   // 100000
  int E = in_sizes[2];         // 1600000

  char* ws = (char*)d_ws;
  size_t off = 0;
  auto take = [&](size_t bytes) -> void* {
    void* p = ws + off;
    off = (off + bytes + 255) & ~(size_t)255;
    return p;
  };
  int*      flag    = (int*)take(256);
  int*      counts  = (int*)take((size_t)n * 4);
  int*      starts  = (int*)take((size_t)n * 4);
  int*      cursor  = (int*)take((size_t)n * 4);
  int*      bsums   = (int*)take(512 * 4);
  float*    tbuf    = (float*)take((size_t)n * 4);
  float*    x0buf   = (float*)take((size_t)n * 4);
  float2*   csr     = (float2*)take((size_t)E * 8);          // {src,ea} pairs
  _Float16* h16     = (_Float16*)take((size_t)n * 128 * 2);  // 25.6 MB
  _Float16* ht16    = (_Float16*)take((size_t)n * 128 * 2);  // 25.6 MB
  // transient src32/tgt32 alias into ht16 (dead before first GEMM writes it)
  int* src32 = (int*)ht16;
  int* tgt32 = src32 + E;   // 2*E*4 = 12.8 MB <= 25.6 MB

  if (off > ws_size) {
    sentinel_kernel<<<ob, 256, 0, stream>>>((float*)d_out, out_size,
                                            1000.0f + (float)(ws_size >> 20));
    return;
  }

  int eb = (E + 255) / 256;
  int nb = (n + 255) / 256;  // 391 <= 512 (scan2 capacity)

  detect_kernel<<<1, 64, 0, stream>>>(ei, flag);
  zero_kernel<<<nb, 256, 0, stream>>>(counts, n);
  cvt_kernel<<<eb, 256, 0, stream>>>(ei, E, n, flag, src32, tgt32, counts);
  scan1_kernel<<<nb, 256, 0, stream>>>(counts, n, starts, bsums);
  scan2_kernel<<<1, 512, 0, stream>>>(bsums, nb);
  scan3_kernel<<<nb, 256, 0, stream>>>(starts, bsums, n, cursor);
  fill_kernel<<<eb, 256, 0, stream>>>(src32, tgt32, ea, E, n, cursor, csr);

  int sb = (int)(((size_t)n * 128 + 255) / 256);
  slice_kernel<<<sb, 256, 0, stream>>>(x, h16, x0buf, n);
  // tnet: W1=t1W (129x64), h-rows 1..128, extra=x0 via row 0
  head_mfma_kernel<<<(n + 63) / 64, 256, 0, stream>>>(h16, x0buf, t1W, t1b, t2W, t2b,
                                                      tbuf, n, 1, 0);

  for (int l = 0; l < 3; l++) {
    gemm_mfma_kernel<<<(n + 63) / 64, 256, 0, stream>>>(h16, convW[l], convb[l], ht16, n);
    agg_kernel<<<(n + 3) / 4, 256, 0, stream>>>((const __half2*)ht16, csr, starts,
                                                counts, edgew[l], (__half2*)h16, n);
  }

  // mlp: W1=l1W (129x64), h-rows 0..127, extra=t via row 128
  head_mfma_kernel<<<(n + 63) / 64, 256, 0, stream>>>(h16, tbuf, l1W, l1b, l2W, l2b,
                                                      (float*)d_out, n, 0, 128);
}

// Round 9
// 673.346 us; speedup vs baseline: 1.1261x; 1.1261x over previous
//
#include <hip/hip_runtime.h>
#include <hip/hip_fp16.h>
#include <math.h>

// ---------------------------------------------------------------------------
// DeepECCNet: 3-layer gated graph conv + t-gate + MLP head.
// v9: (a) CSR fill split: slot_kernel (atomic->slot, coalesced, no dependent
//     scatter) + scatter_kernel (4 indep fire-and-forget 16B scatter stores
//     per thread) — v8's fused fill was latency-bound on atomic->store chains
//     (122 us @ 850 GB/s, VALU 0.4%). (b) CSR record = {src,g0,g1,g2}: all 3
//     layer gates precomputed once; agg reverts to v7's measured-87us shape
//     (x4 unroll, no per-edge transcendentals) + fp16 h write.
// ---------------------------------------------------------------------------

typedef _Float16 f16x8 __attribute__((ext_vector_type(8)));
typedef float f32x4 __attribute__((ext_vector_type(4)));

__device__ __forceinline__ float sigmoidf_(float v) { return 1.f / (1.f + expf(-v)); }

__global__ void sentinel_kernel(float* __restrict__ out, int n, float val) {
  int i = blockIdx.x * 256 + threadIdx.x;
  if (i < n) out[i] = val;
}

__global__ void zero_kernel(int* __restrict__ p, int n) {
  int i = blockIdx.x * 256 + threadIdx.x;
  if (i < n) p[i] = 0;
}

// ---- edge-index dtype hedge: int64 has all-zero hi (odd) words -------------
__global__ void detect_kernel(const int* __restrict__ ei, int* __restrict__ flag) {
  if (threadIdx.x == 0 && blockIdx.x == 0) {
    int all0 = 1;
    for (int i = 1; i < 512; i += 2) {
      if (ei[i] != 0) { all0 = 0; break; }
    }
    *flag = all0;
  }
}

// ---- cvt + degree count in one pass ----------------------------------------
__global__ void cvt_kernel(const int* __restrict__ ei, int E, int n,
                           const int* __restrict__ flag,
                           int* __restrict__ src32, int* __restrict__ tgt32,
                           int* __restrict__ counts) {
  int e = blockIdx.x * blockDim.x + threadIdx.x;
  if (e >= E) return;
  int s, t;
  if (*flag) {
    const long long* e64 = (const long long*)ei;
    s = (int)e64[e];
    t = (int)e64[(size_t)E + e];
  } else {
    s = ei[e];
    t = ei[(size_t)E + e];
  }
  src32[e] = s;
  tgt32[e] = t;
  if ((unsigned)t < (unsigned)n) atomicAdd(&counts[t], 1);
}

__global__ void scan1_kernel(const int* __restrict__ counts, int n,
                             int* __restrict__ starts, int* __restrict__ bsums) {
  __shared__ int tmp[256];
  int i = blockIdx.x * 256 + threadIdx.x;
  int v = (i < n) ? counts[i] : 0;
  tmp[threadIdx.x] = v;
  __syncthreads();
  for (int off = 1; off < 256; off <<= 1) {
    int t = (threadIdx.x >= (unsigned)off) ? tmp[threadIdx.x - off] : 0;
    __syncthreads();
    tmp[threadIdx.x] += t;
    __syncthreads();
  }
  if (i < n) starts[i] = tmp[threadIdx.x] - v;  // exclusive
  if (threadIdx.x == 255) bsums[blockIdx.x] = tmp[255];
}

__global__ void scan2_kernel(int* __restrict__ bsums, int nb) {
  __shared__ int tmp[512];
  int v = (threadIdx.x < (unsigned)nb) ? bsums[threadIdx.x] : 0;
  tmp[threadIdx.x] = v;
  __syncthreads();
  for (int off = 1; off < 512; off <<= 1) {
    int t = (threadIdx.x >= (unsigned)off) ? tmp[threadIdx.x - off] : 0;
    __syncthreads();
    tmp[threadIdx.x] += t;
    __syncthreads();
  }
  if (threadIdx.x < (unsigned)nb) bsums[threadIdx.x] = tmp[threadIdx.x] - v;  // exclusive
}

__global__ void scan3_kernel(int* __restrict__ starts, const int* __restrict__ bsums,
                             int n, int* __restrict__ cursor) {
  int i = blockIdx.x * 256 + threadIdx.x;
  if (i < n) {
    int s = starts[i] + bsums[blockIdx.x];
    starts[i] = s;
    cursor[i] = s;
  }
}

// ---- slot: slot[e] = atomic bump of cursor[tgt[e]] (coalesced write) -------
__global__ void slot_kernel(const int* __restrict__ tgt, int E, int n,
                            int* __restrict__ cursor, int* __restrict__ slot) {
  int e = blockIdx.x * blockDim.x + threadIdx.x;
  if (e >= E) return;
  unsigned t = (unsigned)tgt[e];
  slot[e] = (t < (unsigned)n) ? atomicAdd(&cursor[t], 1) : -1;
}

// ---- scatter: csr[slot[e]] = {src, sig(ea*w0), sig(ea*w1), sig(ea*w2)} -----
// 4 edges/thread, 4 independent fire-and-forget scatter stores.
__global__ void scatter_kernel(const int* __restrict__ src, const int* __restrict__ slot,
                               const float* __restrict__ ea, int E,
                               const float* __restrict__ w0p,
                               const float* __restrict__ w1p,
                               const float* __restrict__ w2p,
                               float4* __restrict__ csr) {
  float w0 = w0p[0], w1 = w1p[0], w2 = w2p[0];
  int base = blockIdx.x * blockDim.x + threadIdx.x;
  int stride = gridDim.x * blockDim.x;
#pragma unroll
  for (int u = 0; u < 4; u++) {
    int e = base + u * stride;
    if (e < E) {
      int sl = slot[e];
      if (sl >= 0 && sl < E) {
        float a = ea[e];
        csr[sl] = make_float4(__int_as_float(src[e]), sigmoidf_(a * w0),
                              sigmoidf_(a * w1), sigmoidf_(a * w2));
      }
    }
  }
}

// ---- h0 = fp16(x[:, 1:]); x0 = x[:, 0] -------------------------------------
__global__ void slice_kernel(const float* __restrict__ x, _Float16* __restrict__ h,
                             float* __restrict__ x0, int n) {
  int idx = blockIdx.x * blockDim.x + threadIdx.x;
  if (idx < n * 128) {
    int node = idx >> 7;
    int k = idx & 127;
    h[idx] = (_Float16)x[(size_t)node * 129 + 1 + k];
  }
  if (idx < n) x0[idx] = x[(size_t)idx * 129];
}

// ---- unified MFMA head: out = sigmoid( relu(h@W1[hrow0:hrow0+128] +
//        extra*W1[xrow] + b1) @ w2 + b2 )
__global__ __launch_bounds__(256) void head_mfma_kernel(const _Float16* __restrict__ h,
    const float* __restrict__ extra, const float* __restrict__ W1,
    const float* __restrict__ b1, const float* __restrict__ w2,
    const float* __restrict__ b2, float* __restrict__ out, int n,
    int hrow0, int xrow) {
  __shared__ __align__(16) _Float16 sB[4 * 4 * 64 * 8];  // 16 KB, B-frag order
  __shared__ float sWx[64], sB1[64], sW2[64];
  for (int idx = threadIdx.x; idx < 8192; idx += 256) {
    int k = idx >> 6, col = idx & 63;
    float w = W1[(size_t)(hrow0 + k) * 64 + col];
    int ks = k >> 5, quad = (k >> 3) & 3, j = k & 7;
    int nt = col >> 4, cl = col & 15;
    sB[(((ks * 4 + nt) * 64) + quad * 16 + cl) * 8 + j] = (_Float16)w;
  }
  if (threadIdx.x < 64) {
    sWx[threadIdx.x] = W1[(size_t)xrow * 64 + threadIdx.x];
    sB1[threadIdx.x] = b1[threadIdx.x];
    sW2[threadIdx.x] = w2[threadIdx.x];
  }
  __syncthreads();
  int wv = threadIdx.x >> 6, lane = threadIdx.x & 63;
  int quad = lane >> 4, l15 = lane & 15;
  int n0 = (blockIdx.x * 4 + wv) * 16;
  if (n0 >= n) return;
  int node_a = min(n0 + l15, n - 1);
  const _Float16* hrow = h + (size_t)node_a * 128 + quad * 8;

  f32x4 acc[4];
#pragma unroll
  for (int t = 0; t < 4; t++) acc[t] = (f32x4){0.f, 0.f, 0.f, 0.f};
  for (int ks = 0; ks < 4; ks++) {
    f16x8 afrag = *(const f16x8*)(hrow + ks * 32);
    const f16x8* bp = (const f16x8*)sB;
#pragma unroll
    for (int t = 0; t < 4; t++) {
      f16x8 bfrag = bp[(ks * 4 + t) * 64 + lane];
      acc[t] = __builtin_amdgcn_mfma_f32_16x16x32_f16(afrag, bfrag, acc[t], 0, 0, 0);
    }
  }
  float b2v = b2[0];
  float xv[4], part[4] = {0.f, 0.f, 0.f, 0.f};
#pragma unroll
  for (int r = 0; r < 4; r++) xv[r] = extra[min(n0 + quad * 4 + r, n - 1)];
#pragma unroll
  for (int t = 0; t < 4; t++) {
    int col = t * 16 + l15;
    float wx = sWx[col], bb = sB1[col], w2v = sW2[col];
#pragma unroll
    for (int r = 0; r < 4; r++) {
      float u = fmaxf(acc[t][r] + xv[r] * wx + bb, 0.f);
      part[r] += u * w2v;
    }
  }
#pragma unroll
  for (int r = 0; r < 4; r++) {
    float p = part[r];
    p += __shfl_xor(p, 1); p += __shfl_xor(p, 2);
    p += __shfl_xor(p, 4); p += __shfl_xor(p, 8);
    int node = n0 + quad * 4 + r;
    if (l15 == 0 && node < n) out[node] = sigmoidf_(p + b2v);
  }
}

// ---- MFMA GEMM: ht16 = f16(h16 @ W + b) ------------------------------------
__global__ __launch_bounds__(256) void gemm_mfma_kernel(const _Float16* __restrict__ h,
    const float* __restrict__ Wg, const float* __restrict__ b,
    _Float16* __restrict__ out16, int n) {
  __shared__ __align__(16) _Float16 sB[4 * 8 * 64 * 8];  // 32 KB
  for (int i = threadIdx.x; i < 4096; i += 256) {  // i = float4 index over W
    int k = i >> 5;
    int n4 = (i & 31) * 4;
    float4 w4 = ((const float4*)Wg)[i];
    int ks = k >> 5, quad = (k >> 3) & 3, j = k & 7;
#pragma unroll
    for (int c = 0; c < 4; c++) {
      int col = n4 + c;
      int nt = col >> 4, cl = col & 15;
      sB[(((ks * 8 + nt) * 64) + quad * 16 + cl) * 8 + j] =
          (_Float16)((const float*)&w4)[c];
    }
  }
  __syncthreads();
  int wv = threadIdx.x >> 6, lane = threadIdx.x & 63;
  int quad = lane >> 4, l15 = lane & 15;
  int n0 = (blockIdx.x * 4 + wv) * 16;
  if (n0 >= n) return;
  int node_a = min(n0 + l15, n - 1);
  const _Float16* hrow = h + (size_t)node_a * 128 + quad * 8;

  f32x4 acc[8];
#pragma unroll
  for (int t = 0; t < 8; t++) acc[t] = (f32x4){0.f, 0.f, 0.f, 0.f};

  for (int ks = 0; ks < 4; ks++) {
    f16x8 afrag = *(const f16x8*)(hrow + ks * 32);
    const f16x8* bp = (const f16x8*)(sB + ks * 8 * 64 * 8);
#pragma unroll
    for (int t = 0; t < 8; t++) {
      f16x8 bfrag = bp[t * 64 + lane];
      acc[t] = __builtin_amdgcn_mfma_f32_16x16x32_f16(afrag, bfrag, acc[t], 0, 0, 0);
    }
  }
#pragma unroll
  for (int t = 0; t < 8; t++) {
    float bias = b[t * 16 + l15];
#pragma unroll
    for (int r = 0; r < 4; r++) {
      int node = n0 + quad * 4 + r;
      if (node < n)
        out16[(size_t)node * 128 + t * 16 + l15] = (_Float16)(acc[t][r] + bias);
    }
  }
}

// ---- aggregation over fp16 rows; gates pre-baked in csr records; x4 --------
// h' = f16( relu( (gs*ht[v] + sum_e g_e*ht[src_e]) / (deg+1) ) )
__global__ __launch_bounds__(256) void agg_kernel(const __half2* __restrict__ ht,
    const float4* __restrict__ csr, const int* __restrict__ starts,
    const int* __restrict__ counts, const float* __restrict__ wp,
    __half2* __restrict__ hout, int n, int layer) {
  int wv = threadIdx.x >> 6, lane = threadIdx.x & 63;
  int node = blockIdx.x * 4 + wv;
  if (node >= n) return;
  int s = starts[node], c = counts[node];
  float gs = sigmoidf_(wp[0]);
  float2 v0 = __half22float2(ht[(size_t)node * 64 + lane]);
  float ax = gs * v0.x, ay = gs * v0.y;
  float bx = 0.f, by = 0.f;
  int j = 0;
  for (; j + 4 <= c; j += 4) {
    float4 r0 = csr[s + j],     r1 = csr[s + j + 1];
    float4 r2 = csr[s + j + 2], r3 = csr[s + j + 3];
    int sn0 = min(max(__float_as_int(r0.x), 0), n - 1);
    int sn1 = min(max(__float_as_int(r1.x), 0), n - 1);
    int sn2 = min(max(__float_as_int(r2.x), 0), n - 1);
    int sn3 = min(max(__float_as_int(r3.x), 0), n - 1);
    float g0 = (layer == 0) ? r0.y : (layer == 1) ? r0.z : r0.w;
    float g1 = (layer == 0) ? r1.y : (layer == 1) ? r1.z : r1.w;
    float g2 = (layer == 0) ? r2.y : (layer == 1) ? r2.z : r2.w;
    float g3 = (layer == 0) ? r3.y : (layer == 1) ? r3.z : r3.w;
    float2 f0 = __half22float2(ht[(size_t)sn0 * 64 + lane]);
    float2 f1 = __half22float2(ht[(size_t)sn1 * 64 + lane]);
    float2 f2 = __half22float2(ht[(size_t)sn2 * 64 + lane]);
    float2 f3 = __half22float2(ht[(size_t)sn3 * 64 + lane]);
    ax += g0 * f0.x; ay += g0 * f0.y;
    bx += g1 * f1.x; by += g1 * f1.y;
    ax += g2 * f2.x; ay += g2 * f2.y;
    bx += g3 * f3.x; by += g3 * f3.y;
  }
  for (; j < c; j++) {
    float4 r = csr[s + j];
    int sn = min(max(__float_as_int(r.x), 0), n - 1);
    float g = (layer == 0) ? r.y : (layer == 1) ? r.z : r.w;
    float2 f = __half22float2(ht[(size_t)sn * 64 + lane]);
    ax += g * f.x; ay += g * f.y;
  }
  ax += bx; ay += by;
  float inv = 1.f / (float)(c + 1);
  ax = fmaxf(ax * inv, 0.f);
  ay = fmaxf(ay * inv, 0.f);
  hout[(size_t)node * 64 + lane] = __floats2half2_rn(ax, ay);
}

// ---------------------------------------------------------------------------
extern "C" void kernel_launch(void* const* d_in, const int* in_sizes, int n_in,
                              void* d_out, int out_size, void* d_ws, size_t ws_size,
                              hipStream_t stream) {
  int ob = (out_size + 255) / 256;

  const float *x, *ea, *l1W, *l1b, *l2W, *l2b, *t1W, *t1b, *t2W, *t2b;
  const float *convW[3], *convb[3], *edgew[3];
  const int* ei;

  if (n_in == 20) {          // tuples flattened to separate entries
    x = (const float*)d_in[0]; ei = (const int*)d_in[1]; ea = (const float*)d_in[2];
    for (int l = 0; l < 3; l++) {
      convW[l] = (const float*)d_in[3 + l];
      convb[l] = (const float*)d_in[6 + l];
      edgew[l] = (const float*)d_in[9 + l];
    }
    l1W = (const float*)d_in[12]; l1b = (const float*)d_in[13];
    l2W = (const float*)d_in[14]; l2b = (const float*)d_in[15];
    t1W = (const float*)d_in[16]; t1b = (const float*)d_in[17];
    t2W = (const float*)d_in[18]; t2b = (const float*)d_in[19];
  } else if (n_in == 14) {   // each tuple is ONE concatenated buffer
    x = (const float*)d_in[0]; ei = (const int*)d_in[1]; ea = (const float*)d_in[2];
    const float* cw = (const float*)d_in[3];
    const float* cb = (const float*)d_in[4];
    const float* ew = (const float*)d_in[5];
    for (int l = 0; l < 3; l++) {
      convW[l] = cw + (size_t)l * 128 * 128;
      convb[l] = cb + (size_t)l * 128;
      edgew[l] = ew + l;
    }
    l1W = (const float*)d_in[6];  l1b = (const float*)d_in[7];
    l2W = (const float*)d_in[8];  l2b = (const float*)d_in[9];
    t1W = (const float*)d_in[10]; t1b = (const float*)d_in[11];
    t2W = (const float*)d_in[12]; t2b = (const float*)d_in[13];
  } else {
    sentinel_kernel<<<ob, 256, 0, stream>>>((float*)d_out, out_size,
                                            900.0f + (float)n_in);
    return;
  }

  int n = in_sizes[0] / 129;   // 100000
  int E = in_sizes[2];         // 1600000

  char* ws = (char*)d_ws;
  size_t off = 0;
  auto take = [&](size_t bytes) -> void* {
    void* p = ws + off;
    off = (off + bytes + 255) & ~(size_t)255;
    return p;
  };
  int*      flag    = (int*)take(256);
  int*      counts  = (int*)take((size_t)n * 4);
  int*      starts  = (int*)take((size_t)n * 4);
  int*      cursor  = (int*)take((size_t)n * 4);
  int*      bsums   = (int*)take(512 * 4);
  float*    tbuf    = (float*)take((size_t)n * 4);
  float*    x0buf   = (float*)take((size_t)n * 4);
  int*      slot    = (int*)take((size_t)E * 4);             // 6.4 MB
  float4*   csr     = (float4*)take((size_t)E * 16);         // 25.6 MB
  _Float16* h16     = (_Float16*)take((size_t)n * 128 * 2);  // 25.6 MB
  _Float16* ht16    = (_Float16*)take((size_t)n * 128 * 2);  // 25.6 MB
  // transient src32/tgt32 alias into ht16 (dead before first GEMM writes it)
  int* src32 = (int*)ht16;
  int* tgt32 = src32 + E;   // 2*E*4 = 12.8 MB <= 25.6 MB

  if (off > ws_size) {
    sentinel_kernel<<<ob, 256, 0, stream>>>((float*)d_out, out_size,
                                            1000.0f + (float)(ws_size >> 20));
    return;
  }

  int eb = (E + 255) / 256;
  int nb = (n + 255) / 256;  // 391 <= 512 (scan2 capacity)

  detect_kernel<<<1, 64, 0, stream>>>(ei, flag);
  zero_kernel<<<nb, 256, 0, stream>>>(counts, n);
  cvt_kernel<<<eb, 256, 0, stream>>>(ei, E, n, flag, src32, tgt32, counts);
  scan1_kernel<<<nb, 256, 0, stream>>>(counts, n, starts, bsums);
  scan2_kernel<<<1, 512, 0, stream>>>(bsums, nb);
  scan3_kernel<<<nb, 256, 0, stream>>>(starts, bsums, n, cursor);
  slot_kernel<<<eb, 256, 0, stream>>>(tgt32, E, n, cursor, slot);
  scatter_kernel<<<(eb + 3) / 4, 256, 0, stream>>>(src32, slot, ea, E,
                                                   edgew[0], edgew[1], edgew[2], csr);

  int sb = (int)(((size_t)n * 128 + 255) / 256);
  slice_kernel<<<sb, 256, 0, stream>>>(x, h16, x0buf, n);
  // tnet: W1=t1W (129x64), h-rows 1..128, extra=x0 via row 0
  head_mfma_kernel<<<(n + 63) / 64, 256, 0, stream>>>(h16, x0buf, t1W, t1b, t2W, t2b,
                                                      tbuf, n, 1, 0);

  for (int l = 0; l < 3; l++) {
    gemm_mfma_kernel<<<(n + 63) / 64, 256, 0, stream>>>(h16, convW[l], convb[l], ht16, n);
    agg_kernel<<<(n + 3) / 4, 256, 0, stream>>>((const __half2*)ht16, csr, starts,
                                                counts, edgew[l], (__half2*)h16, n, l);
  }

  // mlp: W1=l1W (129x64), h-rows 0..127, extra=t via row 128
  head_mfma_kernel<<<(n + 63) / 64, 256, 0, stream>>>(h16, tbuf, l1W, l1b, l2W, l2b,
                                                      (float*)d_out, n, 0, 128);
}

// Round 10
// 617.485 us; speedup vs baseline: 1.2280x; 1.0905x over previous
//
#include <hip/hip_runtime.h>
#include <hip/hip_fp16.h>
#include <math.h>

// ---------------------------------------------------------------------------
// DeepECCNet: 3-layer gated graph conv + t-gate + MLP head.
// v10: (a) slot fused into cvt — the degree-count atomicAdd already returns
//      the within-target rank; scatter uses starts[t]+rank (slot_kernel and
//      its 1.6M-atomic pass deleted). (b) agg templated on LAYER (gate select
//      is compile-time, no cndmask), src clamped once in scatter not per
//      lane, edge-loop unroll 4->8. v9 agg was 82us @ VALUBusy 50% — half
//      the VALU issue was select/clamp overhead.
// ---------------------------------------------------------------------------

typedef _Float16 f16x8 __attribute__((ext_vector_type(8)));
typedef float f32x4 __attribute__((ext_vector_type(4)));

__device__ __forceinline__ float sigmoidf_(float v) { return 1.f / (1.f + expf(-v)); }

__global__ void sentinel_kernel(float* __restrict__ out, int n, float val) {
  int i = blockIdx.x * 256 + threadIdx.x;
  if (i < n) out[i] = val;
}

__global__ void zero_kernel(int* __restrict__ p, int n) {
  int i = blockIdx.x * 256 + threadIdx.x;
  if (i < n) p[i] = 0;
}

// ---- edge-index dtype hedge: int64 has all-zero hi (odd) words -------------
__global__ void detect_kernel(const int* __restrict__ ei, int* __restrict__ flag) {
  if (threadIdx.x == 0 && blockIdx.x == 0) {
    int all0 = 1;
    for (int i = 1; i < 512; i += 2) {
      if (ei[i] != 0) { all0 = 0; break; }
    }
    *flag = all0;
  }
}

// ---- cvt + degree count + rank in one pass ---------------------------------
// The atomicAdd on counts[t] doubles as within-target rank assignment.
__global__ void cvt_kernel(const int* __restrict__ ei, int E, int n,
                           const int* __restrict__ flag,
                           int* __restrict__ src32, int* __restrict__ tgt32,
                           int* __restrict__ slot, int* __restrict__ counts) {
  int e = blockIdx.x * blockDim.x + threadIdx.x;
  if (e >= E) return;
  int s, t;
  if (*flag) {
    const long long* e64 = (const long long*)ei;
    s = (int)e64[e];
    t = (int)e64[(size_t)E + e];
  } else {
    s = ei[e];
    t = ei[(size_t)E + e];
  }
  src32[e] = s;
  tgt32[e] = t;
  slot[e] = ((unsigned)t < (unsigned)n) ? atomicAdd(&counts[t], 1) : -1;
}

__global__ void scan1_kernel(const int* __restrict__ counts, int n,
                             int* __restrict__ starts, int* __restrict__ bsums) {
  __shared__ int tmp[256];
  int i = blockIdx.x * 256 + threadIdx.x;
  int v = (i < n) ? counts[i] : 0;
  tmp[threadIdx.x] = v;
  __syncthreads();
  for (int off = 1; off < 256; off <<= 1) {
    int t = (threadIdx.x >= (unsigned)off) ? tmp[threadIdx.x - off] : 0;
    __syncthreads();
    tmp[threadIdx.x] += t;
    __syncthreads();
  }
  if (i < n) starts[i] = tmp[threadIdx.x] - v;  // exclusive
  if (threadIdx.x == 255) bsums[blockIdx.x] = tmp[255];
}

__global__ void scan2_kernel(int* __restrict__ bsums, int nb) {
  __shared__ int tmp[512];
  int v = (threadIdx.x < (unsigned)nb) ? bsums[threadIdx.x] : 0;
  tmp[threadIdx.x] = v;
  __syncthreads();
  for (int off = 1; off < 512; off <<= 1) {
    int t = (threadIdx.x >= (unsigned)off) ? tmp[threadIdx.x - off] : 0;
    __syncthreads();
    tmp[threadIdx.x] += t;
    __syncthreads();
  }
  if (threadIdx.x < (unsigned)nb) bsums[threadIdx.x] = tmp[threadIdx.x] - v;  // exclusive
}

__global__ void scan3_kernel(int* __restrict__ starts, const int* __restrict__ bsums, int n) {
  int i = blockIdx.x * 256 + threadIdx.x;
  if (i < n) starts[i] += bsums[blockIdx.x];
}

// ---- scatter: csr[starts[t]+rank] = {src, sig(ea*w0), sig(ea*w1), sig(ea*w2)}
// 4 edges/thread, independent fire-and-forget 16B scatter stores.
__global__ void scatter_kernel(const int* __restrict__ src, const int* __restrict__ tgt,
                               const int* __restrict__ slot, const int* __restrict__ starts,
                               const float* __restrict__ ea, int E, int n,
                               const float* __restrict__ w0p,
                               const float* __restrict__ w1p,
                               const float* __restrict__ w2p,
                               float4* __restrict__ csr) {
  float w0 = w0p[0], w1 = w1p[0], w2 = w2p[0];
  int base = blockIdx.x * blockDim.x + threadIdx.x;
  int stride = gridDim.x * blockDim.x;
#pragma unroll
  for (int u = 0; u < 4; u++) {
    int e = base + u * stride;
    if (e < E) {
      int sl = slot[e];
      if (sl >= 0) {
        int pos = starts[tgt[e]] + sl;
        if ((unsigned)pos < (unsigned)E) {
          float a = ea[e];
          int sn = min(max(src[e], 0), n - 1);  // clamp ONCE here, not in agg
          csr[pos] = make_float4(__int_as_float(sn), sigmoidf_(a * w0),
                                 sigmoidf_(a * w1), sigmoidf_(a * w2));
        }
      }
    }
  }
}

// ---- h0 = fp16(x[:, 1:]); x0 = x[:, 0] -------------------------------------
__global__ void slice_kernel(const float* __restrict__ x, _Float16* __restrict__ h,
                             float* __restrict__ x0, int n) {
  int idx = blockIdx.x * blockDim.x + threadIdx.x;
  if (idx < n * 128) {
    int node = idx >> 7;
    int k = idx & 127;
    h[idx] = (_Float16)x[(size_t)node * 129 + 1 + k];
  }
  if (idx < n) x0[idx] = x[(size_t)idx * 129];
}

// ---- unified MFMA head: out = sigmoid( relu(h@W1[hrow0:hrow0+128] +
//        extra*W1[xrow] + b1) @ w2 + b2 )
__global__ __launch_bounds__(256) void head_mfma_kernel(const _Float16* __restrict__ h,
    const float* __restrict__ extra, const float* __restrict__ W1,
    const float* __restrict__ b1, const float* __restrict__ w2,
    const float* __restrict__ b2, float* __restrict__ out, int n,
    int hrow0, int xrow) {
  __shared__ __align__(16) _Float16 sB[4 * 4 * 64 * 8];  // 16 KB, B-frag order
  __shared__ float sWx[64], sB1[64], sW2[64];
  for (int idx = threadIdx.x; idx < 8192; idx += 256) {
    int k = idx >> 6, col = idx & 63;
    float w = W1[(size_t)(hrow0 + k) * 64 + col];
    int ks = k >> 5, quad = (k >> 3) & 3, j = k & 7;
    int nt = col >> 4, cl = col & 15;
    sB[(((ks * 4 + nt) * 64) + quad * 16 + cl) * 8 + j] = (_Float16)w;
  }
  if (threadIdx.x < 64) {
    sWx[threadIdx.x] = W1[(size_t)xrow * 64 + threadIdx.x];
    sB1[threadIdx.x] = b1[threadIdx.x];
    sW2[threadIdx.x] = w2[threadIdx.x];
  }
  __syncthreads();
  int wv = threadIdx.x >> 6, lane = threadIdx.x & 63;
  int quad = lane >> 4, l15 = lane & 15;
  int n0 = (blockIdx.x * 4 + wv) * 16;
  if (n0 >= n) return;
  int node_a = min(n0 + l15, n - 1);
  const _Float16* hrow = h + (size_t)node_a * 128 + quad * 8;

  f32x4 acc[4];
#pragma unroll
  for (int t = 0; t < 4; t++) acc[t] = (f32x4){0.f, 0.f, 0.f, 0.f};
  for (int ks = 0; ks < 4; ks++) {
    f16x8 afrag = *(const f16x8*)(hrow + ks * 32);
    const f16x8* bp = (const f16x8*)sB;
#pragma unroll
    for (int t = 0; t < 4; t++) {
      f16x8 bfrag = bp[(ks * 4 + t) * 64 + lane];
      acc[t] = __builtin_amdgcn_mfma_f32_16x16x32_f16(afrag, bfrag, acc[t], 0, 0, 0);
    }
  }
  float b2v = b2[0];
  float xv[4], part[4] = {0.f, 0.f, 0.f, 0.f};
#pragma unroll
  for (int r = 0; r < 4; r++) xv[r] = extra[min(n0 + quad * 4 + r, n - 1)];
#pragma unroll
  for (int t = 0; t < 4; t++) {
    int col = t * 16 + l15;
    float wx = sWx[col], bb = sB1[col], w2v = sW2[col];
#pragma unroll
    for (int r = 0; r < 4; r++) {
      float u = fmaxf(acc[t][r] + xv[r] * wx + bb, 0.f);
      part[r] += u * w2v;
    }
  }
#pragma unroll
  for (int r = 0; r < 4; r++) {
    float p = part[r];
    p += __shfl_xor(p, 1); p += __shfl_xor(p, 2);
    p += __shfl_xor(p, 4); p += __shfl_xor(p, 8);
    int node = n0 + quad * 4 + r;
    if (l15 == 0 && node < n) out[node] = sigmoidf_(p + b2v);
  }
}

// ---- MFMA GEMM: ht16 = f16(h16 @ W + b) ------------------------------------
__global__ __launch_bounds__(256) void gemm_mfma_kernel(const _Float16* __restrict__ h,
    const float* __restrict__ Wg, const float* __restrict__ b,
    _Float16* __restrict__ out16, int n) {
  __shared__ __align__(16) _Float16 sB[4 * 8 * 64 * 8];  // 32 KB
  for (int i = threadIdx.x; i < 4096; i += 256) {  // i = float4 index over W
    int k = i >> 5;
    int n4 = (i & 31) * 4;
    float4 w4 = ((const float4*)Wg)[i];
    int ks = k >> 5, quad = (k >> 3) & 3, j = k & 7;
#pragma unroll
    for (int c = 0; c < 4; c++) {
      int col = n4 + c;
      int nt = col >> 4, cl = col & 15;
      sB[(((ks * 8 + nt) * 64) + quad * 16 + cl) * 8 + j] =
          (_Float16)((const float*)&w4)[c];
    }
  }
  __syncthreads();
  int wv = threadIdx.x >> 6, lane = threadIdx.x & 63;
  int quad = lane >> 4, l15 = lane & 15;
  int n0 = (blockIdx.x * 4 + wv) * 16;
  if (n0 >= n) return;
  int node_a = min(n0 + l15, n - 1);
  const _Float16* hrow = h + (size_t)node_a * 128 + quad * 8;

  f32x4 acc[8];
#pragma unroll
  for (int t = 0; t < 8; t++) acc[t] = (f32x4){0.f, 0.f, 0.f, 0.f};

  for (int ks = 0; ks < 4; ks++) {
    f16x8 afrag = *(const f16x8*)(hrow + ks * 32);
    const f16x8* bp = (const f16x8*)(sB + ks * 8 * 64 * 8);
#pragma unroll
    for (int t = 0; t < 8; t++) {
      f16x8 bfrag = bp[t * 64 + lane];
      acc[t] = __builtin_amdgcn_mfma_f32_16x16x32_f16(afrag, bfrag, acc[t], 0, 0, 0);
    }
  }
#pragma unroll
  for (int t = 0; t < 8; t++) {
    float bias = b[t * 16 + l15];
#pragma unroll
    for (int r = 0; r < 4; r++) {
      int node = n0 + quad * 4 + r;
      if (node < n)
        out16[(size_t)node * 128 + t * 16 + l15] = (_Float16)(acc[t][r] + bias);
    }
  }
}

// ---- aggregation over fp16 rows; LAYER is compile-time; unroll x8 ----------
// h' = f16( relu( (gs*ht[v] + sum_e g_e*ht[src_e]) / (deg+1) ) )
template <int LAYER>
__global__ __launch_bounds__(256) void agg_kernel(const __half2* __restrict__ ht,
    const float4* __restrict__ csr, const int* __restrict__ starts,
    const int* __restrict__ counts, const float* __restrict__ wp,
    __half2* __restrict__ hout, int n) {
  int wv = threadIdx.x >> 6, lane = threadIdx.x & 63;
  int node = blockIdx.x * 4 + wv;
  if (node >= n) return;
  int s = starts[node], c = counts[node];
  float gs = sigmoidf_(wp[0]);
  float2 v0 = __half22float2(ht[(size_t)node * 64 + lane]);
  float ax = gs * v0.x, ay = gs * v0.y;
  float bx = 0.f, by = 0.f;
  int j = 0;
  for (; j + 8 <= c; j += 8) {
    float4 r[8];
#pragma unroll
    for (int u = 0; u < 8; u++) r[u] = csr[s + j + u];
    float2 f[8];
#pragma unroll
    for (int u = 0; u < 8; u++) {
      int sn = __float_as_int(r[u].x);  // pre-clamped in scatter
      f[u] = __half22float2(ht[(size_t)sn * 64 + lane]);
    }
#pragma unroll
    for (int u = 0; u < 8; u += 2) {
      float ga = (LAYER == 0) ? r[u].y : (LAYER == 1) ? r[u].z : r[u].w;
      float gb = (LAYER == 0) ? r[u + 1].y : (LAYER == 1) ? r[u + 1].z : r[u + 1].w;
      ax += ga * f[u].x;     ay += ga * f[u].y;
      bx += gb * f[u + 1].x; by += gb * f[u + 1].y;
    }
  }
  for (; j < c; j++) {
    float4 r = csr[s + j];
    int sn = __float_as_int(r.x);
    float g = (LAYER == 0) ? r.y : (LAYER == 1) ? r.z : r.w;
    float2 f = __half22float2(ht[(size_t)sn * 64 + lane]);
    ax += g * f.x; ay += g * f.y;
  }
  ax += bx; ay += by;
  float inv = 1.f / (float)(c + 1);
  ax = fmaxf(ax * inv, 0.f);
  ay = fmaxf(ay * inv, 0.f);
  hout[(size_t)node * 64 + lane] = __floats2half2_rn(ax, ay);
}

// ---------------------------------------------------------------------------
extern "C" void kernel_launch(void* const* d_in, const int* in_sizes, int n_in,
                              void* d_out, int out_size, void* d_ws, size_t ws_size,
                              hipStream_t stream) {
  int ob = (out_size + 255) / 256;

  const float *x, *ea, *l1W, *l1b, *l2W, *l2b, *t1W, *t1b, *t2W, *t2b;
  const float *convW[3], *convb[3], *edgew[3];
  const int* ei;

  if (n_in == 20) {          // tuples flattened to separate entries
    x = (const float*)d_in[0]; ei = (const int*)d_in[1]; ea = (const float*)d_in[2];
    for (int l = 0; l < 3; l++) {
      convW[l] = (const float*)d_in[3 + l];
      convb[l] = (const float*)d_in[6 + l];
      edgew[l] = (const float*)d_in[9 + l];
    }
    l1W = (const float*)d_in[12]; l1b = (const float*)d_in[13];
    l2W = (const float*)d_in[14]; l2b = (const float*)d_in[15];
    t1W = (const float*)d_in[16]; t1b = (const float*)d_in[17];
    t2W = (const float*)d_in[18]; t2b = (const float*)d_in[19];
  } else if (n_in == 14) {   // each tuple is ONE concatenated buffer
    x = (const float*)d_in[0]; ei = (const int*)d_in[1]; ea = (const float*)d_in[2];
    const float* cw = (const float*)d_in[3];
    const float* cb = (const float*)d_in[4];
    const float* ew = (const float*)d_in[5];
    for (int l = 0; l < 3; l++) {
      convW[l] = cw + (size_t)l * 128 * 128;
      convb[l] = cb + (size_t)l * 128;
      edgew[l] = ew + l;
    }
    l1W = (const float*)d_in[6];  l1b = (const float*)d_in[7];
    l2W = (const float*)d_in[8];  l2b = (const float*)d_in[9];
    t1W = (const float*)d_in[10]; t1b = (const float*)d_in[11];
    t2W = (const float*)d_in[12]; t2b = (const float*)d_in[13];
  } else {
    sentinel_kernel<<<ob, 256, 0, stream>>>((float*)d_out, out_size,
                                            900.0f + (float)n_in);
    return;
  }

  int n = in_sizes[0] / 129;   // 100000
  int E = in_sizes[2];         // 1600000

  char* ws = (char*)d_ws;
  size_t off = 0;
  auto take = [&](size_t bytes) -> void* {
    void* p = ws + off;
    off = (off + bytes + 255) & ~(size_t)255;
    return p;
  };
  int*      flag    = (int*)take(256);
  int*      counts  = (int*)take((size_t)n * 4);
  int*      starts  = (int*)take((size_t)n * 4);
  int*      bsums   = (int*)take(512 * 4);
  float*    tbuf    = (float*)take((size_t)n * 4);
  float*    x0buf   = (float*)take((size_t)n * 4);
  int*      slot    = (int*)take((size_t)E * 4);             // 6.4 MB
  float4*   csr     = (float4*)take((size_t)E * 16);         // 25.6 MB
  _Float16* h16     = (_Float16*)take((size_t)n * 128 * 2);  // 25.6 MB
  _Float16* ht16    = (_Float16*)take((size_t)n * 128 * 2);  // 25.6 MB
  // transient src32/tgt32 alias into ht16 (dead before first GEMM writes it)
  int* src32 = (int*)ht16;
  int* tgt32 = src32 + E;   // 2*E*4 = 12.8 MB <= 25.6 MB

  if (off > ws_size) {
    sentinel_kernel<<<ob, 256, 0, stream>>>((float*)d_out, out_size,
                                            1000.0f + (float)(ws_size >> 20));
    return;
  }

  int eb = (E + 255) / 256;
  int nb = (n + 255) / 256;  // 391 <= 512 (scan2 capacity)

  detect_kernel<<<1, 64, 0, stream>>>(ei, flag);
  zero_kernel<<<nb, 256, 0, stream>>>(counts, n);
  cvt_kernel<<<eb, 256, 0, stream>>>(ei, E, n, flag, src32, tgt32, slot, counts);
  scan1_kernel<<<nb, 256, 0, stream>>>(counts, n, starts, bsums);
  scan2_kernel<<<1, 512, 0, stream>>>(bsums, nb);
  scan3_kernel<<<nb, 256, 0, stream>>>(starts, bsums, n);
  scatter_kernel<<<(eb + 3) / 4, 256, 0, stream>>>(src32, tgt32, slot, starts, ea, E, n,
                                                   edgew[0], edgew[1], edgew[2], csr);

  int sb = (int)(((size_t)n * 128 + 255) / 256);
  slice_kernel<<<sb, 256, 0, stream>>>(x, h16, x0buf, n);
  // tnet: W1=t1W (129x64), h-rows 1..128, extra=x0 via row 0
  head_mfma_kernel<<<(n + 63) / 64, 256, 0, stream>>>(h16, x0buf, t1W, t1b, t2W, t2b,
                                                      tbuf, n, 1, 0);

  gemm_mfma_kernel<<<(n + 63) / 64, 256, 0, stream>>>(h16, convW[0], convb[0], ht16, n);
  agg_kernel<0><<<(n + 3) / 4, 256, 0, stream>>>((const __half2*)ht16, csr, starts,
                                                 counts, edgew[0], (__half2*)h16, n);
  gemm_mfma_kernel<<<(n + 63) / 64, 256, 0, stream>>>(h16, convW[1], convb[1], ht16, n);
  agg_kernel<1><<<(n + 3) / 4, 256, 0, stream>>>((const __half2*)ht16, csr, starts,
                                                 counts, edgew[1], (__half2*)h16, n);
  gemm_mfma_kernel<<<(n + 63) / 64, 256, 0, stream>>>(h16, convW[2], convb[2], ht16, n);
  agg_kernel<2><<<(n + 3) / 4, 256, 0, stream>>>((const __half2*)ht16, csr, starts,
                                                 counts, edgew[2], (__half2*)h16, n);

  // mlp: W1=l1W (129x64), h-rows 0..127, extra=t via row 128
  head_mfma_kernel<<<(n + 63) / 64, 256, 0, stream>>>(h16, tbuf, l1W, l1b, l2W, l2b,
                                                      (float*)d_out, n, 0, 128);
}

// Round 11
// 609.835 us; speedup vs baseline: 1.2434x; 1.0125x over previous
//
#include <hip/hip_runtime.h>
#include <hip/hip_fp16.h>
#include <math.h>

// ---------------------------------------------------------------------------
// DeepECCNet: 3-layer gated graph conv + t-gate + MLP head.
// v11: (a) agg unroll 8->4 (x8's serial tail regressed: E[c%8]=3.5 dependent
//      gathers/node) + branchless padded tail (zero serial gathers: tail
//      edges fold into the last 4-batch with zeroed gates). (b) init fuses
//      zero+detect; rank_kernel drops src32/tgt32 materialization (scatter
//      reads edge_index directly): -25.6 MB traffic, -1 launch.
// ---------------------------------------------------------------------------

typedef _Float16 f16x8 __attribute__((ext_vector_type(8)));
typedef float f32x4 __attribute__((ext_vector_type(4)));

__device__ __forceinline__ float sigmoidf_(float v) { return 1.f / (1.f + expf(-v)); }

__global__ void sentinel_kernel(float* __restrict__ out, int n, float val) {
  int i = blockIdx.x * 256 + threadIdx.x;
  if (i < n) out[i] = val;
}

// ---- init: zero counts + detect int64 edge_index (all-zero odd words) ------
__global__ void init_kernel(const int* __restrict__ ei, int* __restrict__ flag,
                            int* __restrict__ counts, int n) {
  int i = blockIdx.x * 256 + threadIdx.x;
  if (i < n) counts[i] = 0;
  if (i == 0) {
    int all0 = 1;
    for (int k = 1; k < 512; k += 2) {
      if (ei[k] != 0) { all0 = 0; break; }
    }
    *flag = all0;
  }
}

// ---- rank: slot[e] = within-target rank via counting atomic ----------------
__global__ void rank_kernel(const int* __restrict__ ei, int E, int n,
                            const int* __restrict__ flag,
                            int* __restrict__ slot, int* __restrict__ counts) {
  int e = blockIdx.x * blockDim.x + threadIdx.x;
  if (e >= E) return;
  int t;
  if (*flag) {
    t = (int)((const long long*)ei)[(size_t)E + e];
  } else {
    t = ei[(size_t)E + e];
  }
  slot[e] = ((unsigned)t < (unsigned)n) ? atomicAdd(&counts[t], 1) : -1;
}

__global__ void scan1_kernel(const int* __restrict__ counts, int n,
                             int* __restrict__ starts, int* __restrict__ bsums) {
  __shared__ int tmp[256];
  int i = blockIdx.x * 256 + threadIdx.x;
  int v = (i < n) ? counts[i] : 0;
  tmp[threadIdx.x] = v;
  __syncthreads();
  for (int off = 1; off < 256; off <<= 1) {
    int t = (threadIdx.x >= (unsigned)off) ? tmp[threadIdx.x - off] : 0;
    __syncthreads();
    tmp[threadIdx.x] += t;
    __syncthreads();
  }
  if (i < n) starts[i] = tmp[threadIdx.x] - v;  // exclusive
  if (threadIdx.x == 255) bsums[blockIdx.x] = tmp[255];
}

__global__ void scan2_kernel(int* __restrict__ bsums, int nb) {
  __shared__ int tmp[512];
  int v = (threadIdx.x < (unsigned)nb) ? bsums[threadIdx.x] : 0;
  tmp[threadIdx.x] = v;
  __syncthreads();
  for (int off = 1; off < 512; off <<= 1) {
    int t = (threadIdx.x >= (unsigned)off) ? tmp[threadIdx.x - off] : 0;
    __syncthreads();
    tmp[threadIdx.x] += t;
    __syncthreads();
  }
  if (threadIdx.x < (unsigned)nb) bsums[threadIdx.x] = tmp[threadIdx.x] - v;  // exclusive
}

__global__ void scan3_kernel(int* __restrict__ starts, const int* __restrict__ bsums, int n) {
  int i = blockIdx.x * 256 + threadIdx.x;
  if (i < n) starts[i] += bsums[blockIdx.x];
}

// ---- scatter: csr[starts[t]+rank] = {src, sig(ea*w0), sig(ea*w1), sig(ea*w2)}
// reads edge_index directly; 4 edges/thread, independent 16B scatter stores.
__global__ void scatter_kernel(const int* __restrict__ ei, const int* __restrict__ slot,
                               const int* __restrict__ starts,
                               const float* __restrict__ ea, int E, int n,
                               const int* __restrict__ flag,
                               const float* __restrict__ w0p,
                               const float* __restrict__ w1p,
                               const float* __restrict__ w2p,
                               float4* __restrict__ csr) {
  float w0 = w0p[0], w1 = w1p[0], w2 = w2p[0];
  int f64 = *flag;
  const long long* e64 = (const long long*)ei;
  int base = blockIdx.x * blockDim.x + threadIdx.x;
  int stride = gridDim.x * blockDim.x;
#pragma unroll
  for (int u = 0; u < 4; u++) {
    int e = base + u * stride;
    if (e < E) {
      int sl = slot[e];
      if (sl >= 0) {
        int s, t;
        if (f64) {
          s = (int)e64[e];
          t = (int)e64[(size_t)E + e];
        } else {
          s = ei[e];
          t = ei[(size_t)E + e];
        }
        int pos = starts[t] + sl;
        if ((unsigned)pos < (unsigned)E) {
          float a = ea[e];
          int sn = min(max(s, 0), n - 1);  // clamp once here, not in agg
          csr[pos] = make_float4(__int_as_float(sn), sigmoidf_(a * w0),
                                 sigmoidf_(a * w1), sigmoidf_(a * w2));
        }
      }
    }
  }
}

// ---- h0 = fp16(x[:, 1:]); x0 = x[:, 0] -------------------------------------
__global__ void slice_kernel(const float* __restrict__ x, _Float16* __restrict__ h,
                             float* __restrict__ x0, int n) {
  int idx = blockIdx.x * blockDim.x + threadIdx.x;
  if (idx < n * 128) {
    int node = idx >> 7;
    int k = idx & 127;
    h[idx] = (_Float16)x[(size_t)node * 129 + 1 + k];
  }
  if (idx < n) x0[idx] = x[(size_t)idx * 129];
}

// ---- unified MFMA head: out = sigmoid( relu(h@W1[hrow0:hrow0+128] +
//        extra*W1[xrow] + b1) @ w2 + b2 )
__global__ __launch_bounds__(256) void head_mfma_kernel(const _Float16* __restrict__ h,
    const float* __restrict__ extra, const float* __restrict__ W1,
    const float* __restrict__ b1, const float* __restrict__ w2,
    const float* __restrict__ b2, float* __restrict__ out, int n,
    int hrow0, int xrow) {
  __shared__ __align__(16) _Float16 sB[4 * 4 * 64 * 8];  // 16 KB, B-frag order
  __shared__ float sWx[64], sB1[64], sW2[64];
  for (int idx = threadIdx.x; idx < 8192; idx += 256) {
    int k = idx >> 6, col = idx & 63;
    float w = W1[(size_t)(hrow0 + k) * 64 + col];
    int ks = k >> 5, quad = (k >> 3) & 3, j = k & 7;
    int nt = col >> 4, cl = col & 15;
    sB[(((ks * 4 + nt) * 64) + quad * 16 + cl) * 8 + j] = (_Float16)w;
  }
  if (threadIdx.x < 64) {
    sWx[threadIdx.x] = W1[(size_t)xrow * 64 + threadIdx.x];
    sB1[threadIdx.x] = b1[threadIdx.x];
    sW2[threadIdx.x] = w2[threadIdx.x];
  }
  __syncthreads();
  int wv = threadIdx.x >> 6, lane = threadIdx.x & 63;
  int quad = lane >> 4, l15 = lane & 15;
  int n0 = (blockIdx.x * 4 + wv) * 16;
  if (n0 >= n) return;
  int node_a = min(n0 + l15, n - 1);
  const _Float16* hrow = h + (size_t)node_a * 128 + quad * 8;

  f32x4 acc[4];
#pragma unroll
  for (int t = 0; t < 4; t++) acc[t] = (f32x4){0.f, 0.f, 0.f, 0.f};
  for (int ks = 0; ks < 4; ks++) {
    f16x8 afrag = *(const f16x8*)(hrow + ks * 32);
    const f16x8* bp = (const f16x8*)sB;
#pragma unroll
    for (int t = 0; t < 4; t++) {
      f16x8 bfrag = bp[(ks * 4 + t) * 64 + lane];
      acc[t] = __builtin_amdgcn_mfma_f32_16x16x32_f16(afrag, bfrag, acc[t], 0, 0, 0);
    }
  }
  float b2v = b2[0];
  float xv[4], part[4] = {0.f, 0.f, 0.f, 0.f};
#pragma unroll
  for (int r = 0; r < 4; r++) xv[r] = extra[min(n0 + quad * 4 + r, n - 1)];
#pragma unroll
  for (int t = 0; t < 4; t++) {
    int col = t * 16 + l15;
    float wx = sWx[col], bb = sB1[col], w2v = sW2[col];
#pragma unroll
    for (int r = 0; r < 4; r++) {
      float u = fmaxf(acc[t][r] + xv[r] * wx + bb, 0.f);
      part[r] += u * w2v;
    }
  }
#pragma unroll
  for (int r = 0; r < 4; r++) {
    float p = part[r];
    p += __shfl_xor(p, 1); p += __shfl_xor(p, 2);
    p += __shfl_xor(p, 4); p += __shfl_xor(p, 8);
    int node = n0 + quad * 4 + r;
    if (l15 == 0 && node < n) out[node] = sigmoidf_(p + b2v);
  }
}

// ---- MFMA GEMM: ht16 = f16(h16 @ W + b) ------------------------------------
__global__ __launch_bounds__(256) void gemm_mfma_kernel(const _Float16* __restrict__ h,
    const float* __restrict__ Wg, const float* __restrict__ b,
    _Float16* __restrict__ out16, int n) {
  __shared__ __align__(16) _Float16 sB[4 * 8 * 64 * 8];  // 32 KB
  for (int i = threadIdx.x; i < 4096; i += 256) {  // i = float4 index over W
    int k = i >> 5;
    int n4 = (i & 31) * 4;
    float4 w4 = ((const float4*)Wg)[i];
    int ks = k >> 5, quad = (k >> 3) & 3, j = k & 7;
#pragma unroll
    for (int c = 0; c < 4; c++) {
      int col = n4 + c;
      int nt = col >> 4, cl = col & 15;
      sB[(((ks * 8 + nt) * 64) + quad * 16 + cl) * 8 + j] =
          (_Float16)((const float*)&w4)[c];
    }
  }
  __syncthreads();
  int wv = threadIdx.x >> 6, lane = threadIdx.x & 63;
  int quad = lane >> 4, l15 = lane & 15;
  int n0 = (blockIdx.x * 4 + wv) * 16;
  if (n0 >= n) return;
  int node_a = min(n0 + l15, n - 1);
  const _Float16* hrow = h + (size_t)node_a * 128 + quad * 8;

  f32x4 acc[8];
#pragma unroll
  for (int t = 0; t < 8; t++) acc[t] = (f32x4){0.f, 0.f, 0.f, 0.f};

  for (int ks = 0; ks < 4; ks++) {
    f16x8 afrag = *(const f16x8*)(hrow + ks * 32);
    const f16x8* bp = (const f16x8*)(sB + ks * 8 * 64 * 8);
#pragma unroll
    for (int t = 0; t < 8; t++) {
      f16x8 bfrag = bp[t * 64 + lane];
      acc[t] = __builtin_amdgcn_mfma_f32_16x16x32_f16(afrag, bfrag, acc[t], 0, 0, 0);
    }
  }
#pragma unroll
  for (int t = 0; t < 8; t++) {
    float bias = b[t * 16 + l15];
#pragma unroll
    for (int r = 0; r < 4; r++) {
      int node = n0 + quad * 4 + r;
      if (node < n)
        out16[(size_t)node * 128 + t * 16 + l15] = (_Float16)(acc[t][r] + bias);
    }
  }
}

// ---- aggregation over fp16 rows; LAYER compile-time; x4 + branchless tail --
// h' = f16( relu( (gs*ht[v] + sum_e g_e*ht[src_e]) / (deg+1) ) )
template <int LAYER>
__global__ __launch_bounds__(256) void agg_kernel(const __half2* __restrict__ ht,
    const float4* __restrict__ csr, const int* __restrict__ starts,
    const int* __restrict__ counts, const float* __restrict__ wp,
    __half2* __restrict__ hout, int n) {
  int wv = threadIdx.x >> 6, lane = threadIdx.x & 63;
  int node = blockIdx.x * 4 + wv;
  if (node >= n) return;
  int s = starts[node], c = counts[node];
  float gs = sigmoidf_(wp[0]);
  float2 v0 = __half22float2(ht[(size_t)node * 64 + lane]);
  float ax = gs * v0.x, ay = gs * v0.y;
  float bx = 0.f, by = 0.f;
  for (int j = 0; j < c; j += 4) {
    int rem = c - j;  // >= 1
    float4 r[4];
#pragma unroll
    for (int u = 0; u < 4; u++) {
      int jj = (u < rem) ? (j + u) : (c - 1);  // pad tail with last edge
      r[u] = csr[s + jj];
    }
    float2 f[4];
#pragma unroll
    for (int u = 0; u < 4; u++) {
      int sn = __float_as_int(r[u].x);  // pre-clamped in scatter
      f[u] = __half22float2(ht[(size_t)sn * 64 + lane]);
    }
#pragma unroll
    for (int u = 0; u < 4; u++) {
      float g = (LAYER == 0) ? r[u].y : (LAYER == 1) ? r[u].z : r[u].w;
      g = (u < rem) ? g : 0.f;  // zero gate on padded edges
      if (u & 1) { bx += g * f[u].x; by += g * f[u].y; }
      else       { ax += g * f[u].x; ay += g * f[u].y; }
    }
  }
  ax += bx; ay += by;
  float inv = 1.f / (float)(c + 1);
  ax = fmaxf(ax * inv, 0.f);
  ay = fmaxf(ay * inv, 0.f);
  hout[(size_t)node * 64 + lane] = __floats2half2_rn(ax, ay);
}

// ---------------------------------------------------------------------------
extern "C" void kernel_launch(void* const* d_in, const int* in_sizes, int n_in,
                              void* d_out, int out_size, void* d_ws, size_t ws_size,
                              hipStream_t stream) {
  int ob = (out_size + 255) / 256;

  const float *x, *ea, *l1W, *l1b, *l2W, *l2b, *t1W, *t1b, *t2W, *t2b;
  const float *convW[3], *convb[3], *edgew[3];
  const int* ei;

  if (n_in == 20) {          // tuples flattened to separate entries
    x = (const float*)d_in[0]; ei = (const int*)d_in[1]; ea = (const float*)d_in[2];
    for (int l = 0; l < 3; l++) {
      convW[l] = (const float*)d_in[3 + l];
      convb[l] = (const float*)d_in[6 + l];
      edgew[l] = (const float*)d_in[9 + l];
    }
    l1W = (const float*)d_in[12]; l1b = (const float*)d_in[13];
    l2W = (const float*)d_in[14]; l2b = (const float*)d_in[15];
    t1W = (const float*)d_in[16]; t1b = (const float*)d_in[17];
    t2W = (const float*)d_in[18]; t2b = (const float*)d_in[19];
  } else if (n_in == 14) {   // each tuple is ONE concatenated buffer
    x = (const float*)d_in[0]; ei = (const int*)d_in[1]; ea = (const float*)d_in[2];
    const float* cw = (const float*)d_in[3];
    const float* cb = (const float*)d_in[4];
    const float* ew = (const float*)d_in[5];
    for (int l = 0; l < 3; l++) {
      convW[l] = cw + (size_t)l * 128 * 128;
      convb[l] = cb + (size_t)l * 128;
      edgew[l] = ew + l;
    }
    l1W = (const float*)d_in[6];  l1b = (const float*)d_in[7];
    l2W = (const float*)d_in[8];  l2b = (const float*)d_in[9];
    t1W = (const float*)d_in[10]; t1b = (const float*)d_in[11];
    t2W = (const float*)d_in[12]; t2b = (const float*)d_in[13];
  } else {
    sentinel_kernel<<<ob, 256, 0, stream>>>((float*)d_out, out_size,
                                            900.0f + (float)n_in);
    return;
  }

  int n = in_sizes[0] / 129;   // 100000
  int E = in_sizes[2];         // 1600000

  char* ws = (char*)d_ws;
  size_t off = 0;
  auto take = [&](size_t bytes) -> void* {
    void* p = ws + off;
    off = (off + bytes + 255) & ~(size_t)255;
    return p;
  };
  int*      flag    = (int*)take(256);
  int*      counts  = (int*)take((size_t)n * 4);
  int*      starts  = (int*)take((size_t)n * 4);
  int*      bsums   = (int*)take(512 * 4);
  float*    tbuf    = (float*)take((size_t)n * 4);
  float*    x0buf   = (float*)take((size_t)n * 4);
  int*      slot    = (int*)take((size_t)E * 4);             // 6.4 MB
  float4*   csr     = (float4*)take((size_t)E * 16);         // 25.6 MB
  _Float16* h16     = (_Float16*)take((size_t)n * 128 * 2);  // 25.6 MB
  _Float16* ht16    = (_Float16*)take((size_t)n * 128 * 2);  // 25.6 MB

  if (off > ws_size) {
    sentinel_kernel<<<ob, 256, 0, stream>>>((float*)d_out, out_size,
                                            1000.0f + (float)(ws_size >> 20));
    return;
  }

  int eb = (E + 255) / 256;
  int nb = (n + 255) / 256;  // 391 <= 512 (scan2 capacity)

  init_kernel<<<nb, 256, 0, stream>>>(ei, flag, counts, n);
  rank_kernel<<<eb, 256, 0, stream>>>(ei, E, n, flag, slot, counts);
  scan1_kernel<<<nb, 256, 0, stream>>>(counts, n, starts, bsums);
  scan2_kernel<<<1, 512, 0, stream>>>(bsums, nb);
  scan3_kernel<<<nb, 256, 0, stream>>>(starts, bsums, n);
  scatter_kernel<<<(eb + 3) / 4, 256, 0, stream>>>(ei, slot, starts, ea, E, n, flag,
                                                   edgew[0], edgew[1], edgew[2], csr);

  int sb = (int)(((size_t)n * 128 + 255) / 256);
  slice_kernel<<<sb, 256, 0, stream>>>(x, h16, x0buf, n);
  // tnet: W1=t1W (129x64), h-rows 1..128, extra=x0 via row 0
  head_mfma_kernel<<<(n + 63) / 64, 256, 0, stream>>>(h16, x0buf, t1W, t1b, t2W, t2b,
                                                      tbuf, n, 1, 0);

  gemm_mfma_kernel<<<(n + 63) / 64, 256, 0, stream>>>(h16, convW[0], convb[0], ht16, n);
  agg_kernel<0><<<(n + 3) / 4, 256, 0, stream>>>((const __half2*)ht16, csr, starts,
                                                 counts, edgew[0], (__half2*)h16, n);
  gemm_mfma_kernel<<<(n + 63) / 64, 256, 0, stream>>>(h16, convW[1], convb[1], ht16, n);
  agg_kernel<1><<<(n + 3) / 4, 256, 0, stream>>>((const __half2*)ht16, csr, starts,
                                                 counts, edgew[1], (__half2*)h16, n);
  gemm_mfma_kernel<<<(n + 63) / 64, 256, 0, stream>>>(h16, convW[2], convb[2], ht16, n);
  agg_kernel<2><<<(n + 3) / 4, 256, 0, stream>>>((const __half2*)ht16, csr, starts,
                                                 counts, edgew[2], (__half2*)h16, n);

  // mlp: W1=l1W (129x64), h-rows 0..127, extra=t via row 128
  head_mfma_kernel<<<(n + 63) / 64, 256, 0, stream>>>(h16, tbuf, l1W, l1b, l2W, l2b,
                                                      (float*)d_out, n, 0, 128);
}

// Round 12
// 563.155 us; speedup vs baseline: 1.3465x; 1.0829x over previous
//
#include <hip/hip_runtime.h>
#include <hip/hip_fp16.h>
#include <math.h>

// ---------------------------------------------------------------------------
// DeepECCNet: 3-layer gated graph conv + t-gate + MLP head.
// v12: (a) CSR record packed to 8B: word0 = src(17b) | g0(15b fixed-point),
//      word1 = g1(15b) | g2(15b). Gates are (0,1) sigmoids -> 15-bit quant
//      err 1.5e-5 (noise). agg fetch -12.8MB/layer, scatter write lines
//      halved. agg loop reverted to v9's proven x4+serial-tail shape
//      (padding cndmasks removed; v9=82.0 vs v11=83.6 us).
//      (b) gemm: grid-stride tile loop, 1024 co-resident blocks, W staged
//      once per block (v11: ~6 one-shot blocks/CU, staging unamortized).
// ---------------------------------------------------------------------------

typedef _Float16 f16x8 __attribute__((ext_vector_type(8)));
typedef float f32x4 __attribute__((ext_vector_type(4)));

__device__ __forceinline__ float sigmoidf_(float v) { return 1.f / (1.f + expf(-v)); }

__global__ void sentinel_kernel(float* __restrict__ out, int n, float val) {
  int i = blockIdx.x * 256 + threadIdx.x;
  if (i < n) out[i] = val;
}

// ---- init: zero counts + detect int64 edge_index (all-zero odd words) ------
__global__ void init_kernel(const int* __restrict__ ei, int* __restrict__ flag,
                            int* __restrict__ counts, int n) {
  int i = blockIdx.x * 256 + threadIdx.x;
  if (i < n) counts[i] = 0;
  if (i == 0) {
    int all0 = 1;
    for (int k = 1; k < 512; k += 2) {
      if (ei[k] != 0) { all0 = 0; break; }
    }
    *flag = all0;
  }
}

// ---- rank: slot[e] = within-target rank via counting atomic ----------------
__global__ void rank_kernel(const int* __restrict__ ei, int E, int n,
                            const int* __restrict__ flag,
                            int* __restrict__ slot, int* __restrict__ counts) {
  int e = blockIdx.x * blockDim.x + threadIdx.x;
  if (e >= E) return;
  int t;
  if (*flag) {
    t = (int)((const long long*)ei)[(size_t)E + e];
  } else {
    t = ei[(size_t)E + e];
  }
  slot[e] = ((unsigned)t < (unsigned)n) ? atomicAdd(&counts[t], 1) : -1;
}

__global__ void scan1_kernel(const int* __restrict__ counts, int n,
                             int* __restrict__ starts, int* __restrict__ bsums) {
  __shared__ int tmp[256];
  int i = blockIdx.x * 256 + threadIdx.x;
  int v = (i < n) ? counts[i] : 0;
  tmp[threadIdx.x] = v;
  __syncthreads();
  for (int off = 1; off < 256; off <<= 1) {
    int t = (threadIdx.x >= (unsigned)off) ? tmp[threadIdx.x - off] : 0;
    __syncthreads();
    tmp[threadIdx.x] += t;
    __syncthreads();
  }
  if (i < n) starts[i] = tmp[threadIdx.x] - v;  // exclusive
  if (threadIdx.x == 255) bsums[blockIdx.x] = tmp[255];
}

__global__ void scan2_kernel(int* __restrict__ bsums, int nb) {
  __shared__ int tmp[512];
  int v = (threadIdx.x < (unsigned)nb) ? bsums[threadIdx.x] : 0;
  tmp[threadIdx.x] = v;
  __syncthreads();
  for (int off = 1; off < 512; off <<= 1) {
    int t = (threadIdx.x >= (unsigned)off) ? tmp[threadIdx.x - off] : 0;
    __syncthreads();
    tmp[threadIdx.x] += t;
    __syncthreads();
  }
  if (threadIdx.x < (unsigned)nb) bsums[threadIdx.x] = tmp[threadIdx.x] - v;  // exclusive
}

__global__ void scan3_kernel(int* __restrict__ starts, const int* __restrict__ bsums, int n) {
  int i = blockIdx.x * 256 + threadIdx.x;
  if (i < n) starts[i] += bsums[blockIdx.x];
}

// ---- scatter: csr[starts[t]+rank] = packed {src|g0, g1|g2} (8B) ------------
__global__ void scatter_kernel(const int* __restrict__ ei, const int* __restrict__ slot,
                               const int* __restrict__ starts,
                               const float* __restrict__ ea, int E, int n,
                               const int* __restrict__ flag,
                               const float* __restrict__ w0p,
                               const float* __restrict__ w1p,
                               const float* __restrict__ w2p,
                               uint2* __restrict__ csr) {
  float w0 = w0p[0], w1 = w1p[0], w2 = w2p[0];
  int f64 = *flag;
  const long long* e64 = (const long long*)ei;
  int base = blockIdx.x * blockDim.x + threadIdx.x;
  int stride = gridDim.x * blockDim.x;
#pragma unroll
  for (int u = 0; u < 4; u++) {
    int e = base + u * stride;
    if (e < E) {
      int sl = slot[e];
      if (sl >= 0) {
        int s, t;
        if (f64) {
          s = (int)e64[e];
          t = (int)e64[(size_t)E + e];
        } else {
          s = ei[e];
          t = ei[(size_t)E + e];
        }
        int pos = starts[t] + sl;
        if ((unsigned)pos < (unsigned)E) {
          float a = ea[e];
          unsigned sn = (unsigned)min(max(s, 0), min(n - 1, 0x1ffff));
          unsigned g0 = (unsigned)__float2uint_rn(sigmoidf_(a * w0) * 32767.f);
          unsigned g1 = (unsigned)__float2uint_rn(sigmoidf_(a * w1) * 32767.f);
          unsigned g2 = (unsigned)__float2uint_rn(sigmoidf_(a * w2) * 32767.f);
          csr[pos] = make_uint2(sn | (g0 << 17), g1 | (g2 << 15));
        }
      }
    }
  }
}

// ---- h0 = fp16(x[:, 1:]); x0 = x[:, 0] -------------------------------------
__global__ void slice_kernel(const float* __restrict__ x, _Float16* __restrict__ h,
                             float* __restrict__ x0, int n) {
  int idx = blockIdx.x * blockDim.x + threadIdx.x;
  if (idx < n * 128) {
    int node = idx >> 7;
    int k = idx & 127;
    h[idx] = (_Float16)x[(size_t)node * 129 + 1 + k];
  }
  if (idx < n) x0[idx] = x[(size_t)idx * 129];
}

// ---- unified MFMA head: out = sigmoid( relu(h@W1[hrow0:hrow0+128] +
//        extra*W1[xrow] + b1) @ w2 + b2 )
__global__ __launch_bounds__(256) void head_mfma_kernel(const _Float16* __restrict__ h,
    const float* __restrict__ extra, const float* __restrict__ W1,
    const float* __restrict__ b1, const float* __restrict__ w2,
    const float* __restrict__ b2, float* __restrict__ out, int n,
    int hrow0, int xrow) {
  __shared__ __align__(16) _Float16 sB[4 * 4 * 64 * 8];  // 16 KB, B-frag order
  __shared__ float sWx[64], sB1[64], sW2[64];
  for (int idx = threadIdx.x; idx < 8192; idx += 256) {
    int k = idx >> 6, col = idx & 63;
    float w = W1[(size_t)(hrow0 + k) * 64 + col];
    int ks = k >> 5, quad = (k >> 3) & 3, j = k & 7;
    int nt = col >> 4, cl = col & 15;
    sB[(((ks * 4 + nt) * 64) + quad * 16 + cl) * 8 + j] = (_Float16)w;
  }
  if (threadIdx.x < 64) {
    sWx[threadIdx.x] = W1[(size_t)xrow * 64 + threadIdx.x];
    sB1[threadIdx.x] = b1[threadIdx.x];
    sW2[threadIdx.x] = w2[threadIdx.x];
  }
  __syncthreads();
  int wv = threadIdx.x >> 6, lane = threadIdx.x & 63;
  int quad = lane >> 4, l15 = lane & 15;
  int n0 = (blockIdx.x * 4 + wv) * 16;
  if (n0 >= n) return;
  int node_a = min(n0 + l15, n - 1);
  const _Float16* hrow = h + (size_t)node_a * 128 + quad * 8;

  f32x4 acc[4];
#pragma unroll
  for (int t = 0; t < 4; t++) acc[t] = (f32x4){0.f, 0.f, 0.f, 0.f};
  for (int ks = 0; ks < 4; ks++) {
    f16x8 afrag = *(const f16x8*)(hrow + ks * 32);
    const f16x8* bp = (const f16x8*)sB;
#pragma unroll
    for (int t = 0; t < 4; t++) {
      f16x8 bfrag = bp[(ks * 4 + t) * 64 + lane];
      acc[t] = __builtin_amdgcn_mfma_f32_16x16x32_f16(afrag, bfrag, acc[t], 0, 0, 0);
    }
  }
  float b2v = b2[0];
  float xv[4], part[4] = {0.f, 0.f, 0.f, 0.f};
#pragma unroll
  for (int r = 0; r < 4; r++) xv[r] = extra[min(n0 + quad * 4 + r, n - 1)];
#pragma unroll
  for (int t = 0; t < 4; t++) {
    int col = t * 16 + l15;
    float wx = sWx[col], bb = sB1[col], w2v = sW2[col];
#pragma unroll
    for (int r = 0; r < 4; r++) {
      float u = fmaxf(acc[t][r] + xv[r] * wx + bb, 0.f);
      part[r] += u * w2v;
    }
  }
#pragma unroll
  for (int r = 0; r < 4; r++) {
    float p = part[r];
    p += __shfl_xor(p, 1); p += __shfl_xor(p, 2);
    p += __shfl_xor(p, 4); p += __shfl_xor(p, 8);
    int node = n0 + quad * 4 + r;
    if (l15 == 0 && node < n) out[node] = sigmoidf_(p + b2v);
  }
}

// ---- MFMA GEMM: ht16 = f16(h16 @ W + b); grid-stride over 64-node tiles ----
__global__ __launch_bounds__(256) void gemm_mfma_kernel(const _Float16* __restrict__ h,
    const float* __restrict__ Wg, const float* __restrict__ b,
    _Float16* __restrict__ out16, int n) {
  __shared__ __align__(16) _Float16 sB[4 * 8 * 64 * 8];  // 32 KB
  for (int i = threadIdx.x; i < 4096; i += 256) {  // i = float4 index over W
    int k = i >> 5;
    int n4 = (i & 31) * 4;
    float4 w4 = ((const float4*)Wg)[i];
    int ks = k >> 5, quad = (k >> 3) & 3, j = k & 7;
#pragma unroll
    for (int c = 0; c < 4; c++) {
      int col = n4 + c;
      int nt = col >> 4, cl = col & 15;
      sB[(((ks * 8 + nt) * 64) + quad * 16 + cl) * 8 + j] =
          (_Float16)((const float*)&w4)[c];
    }
  }
  __syncthreads();
  int wv = threadIdx.x >> 6, lane = threadIdx.x & 63;
  int quad = lane >> 4, l15 = lane & 15;
  int tiles = (n + 63) >> 6;
  for (int tile = blockIdx.x; tile < tiles; tile += gridDim.x) {
    int n0 = (tile * 4 + wv) * 16;
    if (n0 >= n) continue;
    int node_a = min(n0 + l15, n - 1);
    const _Float16* hrow = h + (size_t)node_a * 128 + quad * 8;

    f32x4 acc[8];
#pragma unroll
    for (int t = 0; t < 8; t++) acc[t] = (f32x4){0.f, 0.f, 0.f, 0.f};

    for (int ks = 0; ks < 4; ks++) {
      f16x8 afrag = *(const f16x8*)(hrow + ks * 32);
      const f16x8* bp = (const f16x8*)(sB + ks * 8 * 64 * 8);
#pragma unroll
      for (int t = 0; t < 8; t++) {
        f16x8 bfrag = bp[t * 64 + lane];
        acc[t] = __builtin_amdgcn_mfma_f32_16x16x32_f16(afrag, bfrag, acc[t], 0, 0, 0);
      }
    }
#pragma unroll
    for (int t = 0; t < 8; t++) {
      float bias = b[t * 16 + l15];
#pragma unroll
      for (int r = 0; r < 4; r++) {
        int node = n0 + quad * 4 + r;
        if (node < n)
          out16[(size_t)node * 128 + t * 16 + l15] = (_Float16)(acc[t][r] + bias);
      }
    }
  }
}

// ---- aggregation: fp16 rows, packed 8B records, v9-shape x4 + serial tail --
// h' = f16( relu( (gs*ht[v] + sum_e g_e*ht[src_e]) / (deg+1) ) )
template <int LAYER>
__device__ __forceinline__ float gate_(uint2 r) {
  const float inv = 1.f / 32767.f;
  if (LAYER == 0) return (float)(r.x >> 17) * inv;
  if (LAYER == 1) return (float)(r.y & 0x7fffu) * inv;
  return (float)(r.y >> 15) * inv;
}

template <int LAYER>
__global__ __launch_bounds__(256) void agg_kernel(const __half2* __restrict__ ht,
    const uint2* __restrict__ csr, const int* __restrict__ starts,
    const int* __restrict__ counts, const float* __restrict__ wp,
    __half2* __restrict__ hout, int n) {
  int wv = threadIdx.x >> 6, lane = threadIdx.x & 63;
  int node = blockIdx.x * 4 + wv;
  if (node >= n) return;
  int s = starts[node], c = counts[node];
  float gs = sigmoidf_(wp[0]);
  float2 v0 = __half22float2(ht[(size_t)node * 64 + lane]);
  float ax = gs * v0.x, ay = gs * v0.y;
  float bx = 0.f, by = 0.f;
  int j = 0;
  for (; j + 4 <= c; j += 4) {
    uint2 r0 = csr[s + j],     r1 = csr[s + j + 1];
    uint2 r2 = csr[s + j + 2], r3 = csr[s + j + 3];
    int sn0 = r0.x & 0x1ffffu, sn1 = r1.x & 0x1ffffu;
    int sn2 = r2.x & 0x1ffffu, sn3 = r3.x & 0x1ffffu;
    float g0 = gate_<LAYER>(r0), g1 = gate_<LAYER>(r1);
    float g2 = gate_<LAYER>(r2), g3 = gate_<LAYER>(r3);
    float2 f0 = __half22float2(ht[(size_t)sn0 * 64 + lane]);
    float2 f1 = __half22float2(ht[(size_t)sn1 * 64 + lane]);
    float2 f2 = __half22float2(ht[(size_t)sn2 * 64 + lane]);
    float2 f3 = __half22float2(ht[(size_t)sn3 * 64 + lane]);
    ax += g0 * f0.x; ay += g0 * f0.y;
    bx += g1 * f1.x; by += g1 * f1.y;
    ax += g2 * f2.x; ay += g2 * f2.y;
    bx += g3 * f3.x; by += g3 * f3.y;
  }
  for (; j < c; j++) {
    uint2 r = csr[s + j];
    int sn = r.x & 0x1ffffu;
    float g = gate_<LAYER>(r);
    float2 f = __half22float2(ht[(size_t)sn * 64 + lane]);
    ax += g * f.x; ay += g * f.y;
  }
  ax += bx; ay += by;
  float inv = 1.f / (float)(c + 1);
  ax = fmaxf(ax * inv, 0.f);
  ay = fmaxf(ay * inv, 0.f);
  hout[(size_t)node * 64 + lane] = __floats2half2_rn(ax, ay);
}

// ---------------------------------------------------------------------------
extern "C" void kernel_launch(void* const* d_in, const int* in_sizes, int n_in,
                              void* d_out, int out_size, void* d_ws, size_t ws_size,
                              hipStream_t stream) {
  int ob = (out_size + 255) / 256;

  const float *x, *ea, *l1W, *l1b, *l2W, *l2b, *t1W, *t1b, *t2W, *t2b;
  const float *convW[3], *convb[3], *edgew[3];
  const int* ei;

  if (n_in == 20) {          // tuples flattened to separate entries
    x = (const float*)d_in[0]; ei = (const int*)d_in[1]; ea = (const float*)d_in[2];
    for (int l = 0; l < 3; l++) {
      convW[l] = (const float*)d_in[3 + l];
      convb[l] = (const float*)d_in[6 + l];
      edgew[l] = (const float*)d_in[9 + l];
    }
    l1W = (const float*)d_in[12]; l1b = (const float*)d_in[13];
    l2W = (const float*)d_in[14]; l2b = (const float*)d_in[15];
    t1W = (const float*)d_in[16]; t1b = (const float*)d_in[17];
    t2W = (const float*)d_in[18]; t2b = (const float*)d_in[19];
  } else if (n_in == 14) {   // each tuple is ONE concatenated buffer
    x = (const float*)d_in[0]; ei = (const int*)d_in[1]; ea = (const float*)d_in[2];
    const float* cw = (const float*)d_in[3];
    const float* cb = (const float*)d_in[4];
    const float* ew = (const float*)d_in[5];
    for (int l = 0; l < 3; l++) {
      convW[l] = cw + (size_t)l * 128 * 128;
      convb[l] = cb + (size_t)l * 128;
      edgew[l] = ew + l;
    }
    l1W = (const float*)d_in[6];  l1b = (const float*)d_in[7];
    l2W = (const float*)d_in[8];  l2b = (const float*)d_in[9];
    t1W = (const float*)d_in[10]; t1b = (const float*)d_in[11];
    t2W = (const float*)d_in[12]; t2b = (const float*)d_in[13];
  } else {
    sentinel_kernel<<<ob, 256, 0, stream>>>((float*)d_out, out_size,
                                            900.0f + (float)n_in);
    return;
  }

  int n = in_sizes[0] / 129;   // 100000
  int E = in_sizes[2];         // 1600000

  char* ws = (char*)d_ws;
  size_t off = 0;
  auto take = [&](size_t bytes) -> void* {
    void* p = ws + off;
    off = (off + bytes + 255) & ~(size_t)255;
    return p;
  };
  int*      flag    = (int*)take(256);
  int*      counts  = (int*)take((size_t)n * 4);
  int*      starts  = (int*)take((size_t)n * 4);
  int*      bsums   = (int*)take(512 * 4);
  float*    tbuf    = (float*)take((size_t)n * 4);
  float*    x0buf   = (float*)take((size_t)n * 4);
  int*      slot    = (int*)take((size_t)E * 4);             // 6.4 MB
  uint2*    csr     = (uint2*)take((size_t)E * 8);           // 12.8 MB
  _Float16* h16     = (_Float16*)take((size_t)n * 128 * 2);  // 25.6 MB
  _Float16* ht16    = (_Float16*)take((size_t)n * 128 * 2);  // 25.6 MB

  if (off > ws_size) {
    sentinel_kernel<<<ob, 256, 0, stream>>>((float*)d_out, out_size,
                                            1000.0f + (float)(ws_size >> 20));
    return;
  }

  int eb = (E + 255) / 256;
  int nb = (n + 255) / 256;  // 391 <= 512 (scan2 capacity)

  init_kernel<<<nb, 256, 0, stream>>>(ei, flag, counts, n);
  rank_kernel<<<eb, 256, 0, stream>>>(ei, E, n, flag, slot, counts);
  scan1_kernel<<<nb, 256, 0, stream>>>(counts, n, starts, bsums);
  scan2_kernel<<<1, 512, 0, stream>>>(bsums, nb);
  scan3_kernel<<<nb, 256, 0, stream>>>(starts, bsums, n);
  scatter_kernel<<<(eb + 3) / 4, 256, 0, stream>>>(ei, slot, starts, ea, E, n, flag,
                                                   edgew[0], edgew[1], edgew[2], csr);

  int sb = (int)(((size_t)n * 128 + 255) / 256);
  slice_kernel<<<sb, 256, 0, stream>>>(x, h16, x0buf, n);
  // tnet: W1=t1W (129x64), h-rows 1..128, extra=x0 via row 0
  head_mfma_kernel<<<(n + 63) / 64, 256, 0, stream>>>(h16, x0buf, t1W, t1b, t2W, t2b,
                                                      tbuf, n, 1, 0);

  int gemm_grid = min((n + 63) / 64, 1024);
  gemm_mfma_kernel<<<gemm_grid, 256, 0, stream>>>(h16, convW[0], convb[0], ht16, n);
  agg_kernel<0><<<(n + 3) / 4, 256, 0, stream>>>((const __half2*)ht16, csr, starts,
                                                 counts, edgew[0], (__half2*)h16, n);
  gemm_mfma_kernel<<<gemm_grid, 256, 0, stream>>>(h16, convW[1], convb[1], ht16, n);
  agg_kernel<1><<<(n + 3) / 4, 256, 0, stream>>>((const __half2*)ht16, csr, starts,
                                                 counts, edgew[1], (__half2*)h16, n);
  gemm_mfma_kernel<<<gemm_grid, 256, 0, stream>>>(h16, convW[2], convb[2], ht16, n);
  agg_kernel<2><<<(n + 3) / 4, 256, 0, stream>>>((const __half2*)ht16, csr, starts,
                                                 counts, edgew[2], (__half2*)h16, n);

  // mlp: W1=l1W (129x64), h-rows 0..127, extra=t via row 128
  head_mfma_kernel<<<(n + 63) / 64, 256, 0, stream>>>(h16, tbuf, l1W, l1b, l2W, l2b,
                                                      (float*)d_out, n, 0, 128);
}